// Round 3
// baseline (283.135 us; speedup 1.0000x reference)
//
#include <hip/hip_runtime.h>
#include <hip/hip_bf16.h>

// B=4, Q=K=1024, C=512, H=8, HD=64, OUT=512
// d_out = [output (4*1024*512 f32) | logits_update (4*8*1024*1024 f32)]

typedef float f32x4 __attribute__((ext_vector_type(4)));
typedef __bf16 bf16x8 __attribute__((ext_vector_type(8)));
typedef __bf16 bf16x4 __attribute__((ext_vector_type(4)));

static __device__ __forceinline__ __bf16 f2bf(float x) {
    union { float f; unsigned int u; } c; c.f = x;
    unsigned int r = (c.u + 0x7fffu + ((c.u >> 16) & 1u)) >> 16;
    union { unsigned short s; __bf16 b; } o; o.s = (unsigned short)r;
    return o.b;
}

// async global->LDS, 16B per lane; LDS dest = wave-uniform base + lane*16
static __device__ __forceinline__ void async16(const void* g, void* l) {
    __builtin_amdgcn_global_load_lds(
        (const __attribute__((address_space(1))) void*)g,
        (__attribute__((address_space(3))) void*)l, 16, 0, 0);
}

// ---------------------------------------------------------------------------
// Cast q_data/m_data f32 -> bf16, vectorized (8 elem/thread each).
// ---------------------------------------------------------------------------
__global__ __launch_bounds__(256) void cast_data(
    const float* __restrict__ qd, const float* __restrict__ md,
    __bf16* __restrict__ qdb, __bf16* __restrict__ mdb)
{
    const int i = blockIdx.x * 256 + threadIdx.x;   // 0..262143
    const f32x4* q4 = (const f32x4*)qd;
    const f32x4* m4 = (const f32x4*)md;
    f32x4 a = q4[2 * i], b = q4[2 * i + 1];
    bf16x8 o;
#pragma unroll
    for (int j = 0; j < 4; j++) { o[j] = f2bf(a[j]); o[4 + j] = f2bf(b[j]); }
    *(bf16x8*)&qdb[i * 8] = o;
    a = m4[2 * i]; b = m4[2 * i + 1];
#pragma unroll
    for (int j = 0; j < 4; j++) { o[j] = f2bf(a[j]); o[4 + j] = f2bf(b[j]); }
    *(bf16x8*)&mdb[i * 8] = o;
}

// ---------------------------------------------------------------------------
// Tiled transpose+cast of the five 512x512 weight matrices (z selects).
// out[n*512+a] = in[a*512+n] * scale  (qw gets 1/8 folded in)
// ---------------------------------------------------------------------------
__global__ __launch_bounds__(256) void transpose_cast(
    const float* __restrict__ qw, const float* __restrict__ kw,
    const float* __restrict__ vw, const float* __restrict__ gw,
    const float* __restrict__ ow,
    __bf16* __restrict__ qwt, __bf16* __restrict__ kwt,
    __bf16* __restrict__ vwt, __bf16* __restrict__ gwt,
    __bf16* __restrict__ owt)
{
    __shared__ float tile[64][65];
    const int z = blockIdx.z;
    const float* src = (z == 0) ? qw : (z == 1) ? kw : (z == 2) ? vw : (z == 3) ? gw : ow;
    __bf16* dst = (z == 0) ? qwt : (z == 1) ? kwt : (z == 2) ? vwt : (z == 3) ? gwt : owt;
    const float scale = (z == 0) ? 0.125f : 1.0f;
    const int a0 = blockIdx.x * 64, n0 = blockIdx.y * 64;
    const int t = threadIdx.x, tr = t >> 4, tc = (t & 15) * 4;
#pragma unroll
    for (int ii = 0; ii < 4; ii++) {
        f32x4 v = *(const f32x4*)&src[(a0 + tr + 16 * ii) * 512 + n0 + tc];
#pragma unroll
        for (int j = 0; j < 4; j++) tile[tr + 16 * ii][tc + j] = v[j] * scale;
    }
    __syncthreads();
#pragma unroll
    for (int ii = 0; ii < 4; ii++) {
        const int nr = tr + 16 * ii;
        bf16x4 o;
#pragma unroll
        for (int j = 0; j < 4; j++) o[j] = f2bf(tile[tc + j][nr]);
        *(bf16x4*)&dst[(n0 + nr) * 512 + a0 + tc] = o;
    }
}

// ---------------------------------------------------------------------------
// 128x128-tile bf16 GEMM core, K=512 (m97 structure: 874 TF-class).
// 4 waves in 2x2 arrangement, each computes 64x64 via 4x4 MFMA accumulators.
// ---------------------------------------------------------------------------
static __device__ __forceinline__ void gemm_core128(
    const __bf16* __restrict__ A, const __bf16* __restrict__ Bt,
    __bf16* As, __bf16* Bs, int m0, int n0, int t, f32x4 acc[4][4])
{
    const int w = t >> 6, lane = t & 63, quad = lane >> 4, col = lane & 15;
    const int wm = w & 1, wn = w >> 1;
    const int sr = t >> 2, sc = (t & 3) * 8;
    for (int kk = 0; kk < 512; kk += 32) {
        __syncthreads();
        async16(&A[(m0 + sr) * 512 + kk + sc], &As[w * 512]);
        async16(&A[(m0 + sr + 64) * 512 + kk + sc], &As[2048 + w * 512]);
        async16(&Bt[(n0 + sr) * 512 + kk + sc], &Bs[w * 512]);
        async16(&Bt[(n0 + sr + 64) * 512 + kk + sc], &Bs[2048 + w * 512]);
        __syncthreads();
        bf16x8 af[4], bfr[4];
#pragma unroll
        for (int mi = 0; mi < 4; mi++)
            af[mi] = *(const bf16x8*)&As[(wm * 64 + mi * 16 + col) * 32 + quad * 8];
#pragma unroll
        for (int ni = 0; ni < 4; ni++)
            bfr[ni] = *(const bf16x8*)&Bs[(wn * 64 + ni * 16 + col) * 32 + quad * 8];
#pragma unroll
        for (int mi = 0; mi < 4; mi++)
#pragma unroll
            for (int ni = 0; ni < 4; ni++)
                acc[mi][ni] = __builtin_amdgcn_mfma_f32_16x16x32_bf16(af[mi], bfr[ni], acc[mi][ni], 0, 0, 0);
    }
}

// ---------------------------------------------------------------------------
// Merged projection GEMMs (128x128 tiles): z=0 q (b,h,pos,c); z=1 k;
// z=2 v transposed (b,h,c,pos); z=3 gate sigmoid (m,512).
// ---------------------------------------------------------------------------
__global__ __launch_bounds__(256) void proj_gemm(
    const __bf16* __restrict__ qdb, const __bf16* __restrict__ mdb,
    const __bf16* __restrict__ qwt, const __bf16* __restrict__ kwt,
    const __bf16* __restrict__ vwt, const __bf16* __restrict__ gwt,
    __bf16* __restrict__ qbuf, __bf16* __restrict__ kbuf,
    __bf16* __restrict__ vt, __bf16* __restrict__ gate,
    const float* __restrict__ gb)
{
    __shared__ __attribute__((aligned(16))) __bf16 As[4096];
    __shared__ __attribute__((aligned(16))) __bf16 Bs[4096];
    const int z = blockIdx.z;
    const __bf16* A = (z == 0 || z == 3) ? qdb : mdb;
    const __bf16* Bt = (z == 0) ? qwt : (z == 1) ? kwt : (z == 2) ? vwt : gwt;
    const int m0 = blockIdx.x * 128, n0 = blockIdx.y * 128;
    f32x4 acc[4][4];
#pragma unroll
    for (int i = 0; i < 4; i++)
#pragma unroll
        for (int j = 0; j < 4; j++) acc[i][j] = (f32x4){0.f, 0.f, 0.f, 0.f};
    gemm_core128(A, Bt, As, Bs, m0, n0, threadIdx.x, acc);

    const int t = threadIdx.x, w = t >> 6, quad = (t >> 4) & 3, col = t & 15;
    const int wm = w & 1, wn = w >> 1;
#pragma unroll
    for (int mi = 0; mi < 4; mi++) {
        const int mrow0 = m0 + wm * 64 + mi * 16 + quad * 4;
#pragma unroll
        for (int ni = 0; ni < 4; ni++) {
            const int ncol = n0 + wn * 64 + ni * 16 + col;
#pragma unroll
            for (int r = 0; r < 4; r++) {
                const int m = mrow0 + r;
                const float v = acc[mi][ni][r];
                if (z <= 1) {
                    int b = m >> 10, pos = m & 1023, hh = ncol >> 6, c = ncol & 63;
                    __bf16* o = z ? kbuf : qbuf;
                    o[(((b * 8 + hh) * 1024 + pos) << 6) + c] = f2bf(v);
                } else if (z == 2) {
                    int b = m >> 10, pos = m & 1023, hh = ncol >> 6, c = ncol & 63;
                    vt[((((b * 8 + hh) << 6) + c) << 10) + pos] = f2bf(v);
                } else {
                    float g = 1.0f / (1.0f + __expf(-(v + gb[ncol])));
                    gate[m * 512 + ncol] = f2bf(g);
                }
            }
        }
    }
}

// ---------------------------------------------------------------------------
// Output GEMM (128x128 tiles): out[m,n] = wavg @ ow_t + output_b  (f32 out)
// ---------------------------------------------------------------------------
__global__ __launch_bounds__(256) void out_gemm(
    const __bf16* __restrict__ A, const __bf16* __restrict__ Bt,
    float* __restrict__ outp, const float* __restrict__ bvec)
{
    __shared__ __attribute__((aligned(16))) __bf16 As[4096];
    __shared__ __attribute__((aligned(16))) __bf16 Bs[4096];
    const int m0 = blockIdx.x * 128, n0 = blockIdx.y * 128;
    f32x4 acc[4][4];
#pragma unroll
    for (int i = 0; i < 4; i++)
#pragma unroll
        for (int j = 0; j < 4; j++) acc[i][j] = (f32x4){0.f, 0.f, 0.f, 0.f};
    gemm_core128(A, Bt, As, Bs, m0, n0, threadIdx.x, acc);

    const int t = threadIdx.x, w = t >> 6, quad = (t >> 4) & 3, col = t & 15;
    const int wm = w & 1, wn = w >> 1;
#pragma unroll
    for (int mi = 0; mi < 4; mi++) {
        const int mrow0 = m0 + wm * 64 + mi * 16 + quad * 4;
#pragma unroll
        for (int ni = 0; ni < 4; ni++) {
            const int ncol = n0 + wn * 64 + ni * 16 + col;
#pragma unroll
            for (int r = 0; r < 4; r++)
                outp[(mrow0 + r) * 512 + ncol] = acc[mi][ni][r] + bvec[ncol];
        }
    }
}

// ---------------------------------------------------------------------------
// Attention, max-free flash. Per block: (b,h, 32 q-rows); grid (32,32)=1024
// blocks (4/CU). 4 waves = 2 row-groups x 2 key-halves; each wave: 16 q-rows
// x 32 keys per 64-key tile. nb/bias register-pipelined one iter ahead (the
// per-iter barrier's vmcnt(0) drain guarantees stall-free consumption).
// Wave-pair partial O/l combined via LDS at the end (max-free => additive).
// ---------------------------------------------------------------------------
__global__ __launch_bounds__(256) void attn_kernel(
    const __bf16* __restrict__ qb, const __bf16* __restrict__ kb,
    const __bf16* __restrict__ vt, const float* __restrict__ bias,
    const float* __restrict__ nb, const __bf16* __restrict__ gate,
    float* __restrict__ logits_out, __bf16* __restrict__ wout)
{
    __shared__ __attribute__((aligned(16))) __bf16 qs_ps[2560];  // q tile, then P buf
    __shared__ __attribute__((aligned(16))) __bf16 ks[2][4096];
    __shared__ __attribute__((aligned(16))) __bf16 vs[2][4096];

    const int bh = blockIdx.y, b = bh >> 3, h = bh & 7;
    const int q0 = blockIdx.x * 32;
    const int t = threadIdx.x, lane = t & 63, w = t >> 6;
    const int rg = w >> 1, kw = w & 1;
    const int quad = lane >> 4, col = lane & 15;

    const __bf16* qg = qb + (bh * 1024 + q0) * 64;
    const __bf16* kg = kb + bh * 65536;
    const __bf16* vg = vt + bh * 65536;

    // staging: thread t stages 16B chunk (row r0, chunk c0), XOR-swizzled
    const int r0 = t >> 3, c0 = t & 7;
    const int sw = ((c0 ^ (r0 & 7)) << 3);

    async16(&qg[r0 * 64 + sw], &qs_ps[w * 512]);
    async16(&kg[r0 * 64 + sw], &ks[0][w * 512]);
    async16(&kg[(r0 + 32) * 64 + sw], &ks[0][2048 + w * 512]);
    async16(&vg[r0 * 1024 + sw], &vs[0][w * 512]);
    async16(&vg[(r0 + 32) * 1024 + sw], &vs[0][2048 + w * 512]);

    // nb/bias register pipeline: element (r,n2) of iter kbi lives at
    // nbg[r*1024 + kbi*64 + n2*16] / biasg[kbi*64 + n2*16]
    const float* nbg = nb + (size_t)(h * 1024 + q0 + rg * 16 + quad * 4) * 1024 + kw * 32 + col;
    const float* biasg = bias + b * 1024 + kw * 32 + col;
    float nbv[2][4], bv[2];
#pragma unroll
    for (int n2 = 0; n2 < 2; n2++) {
        bv[n2] = biasg[n2 * 16];
#pragma unroll
        for (int r = 0; r < 4; r++) nbv[n2][r] = nbg[r * 1024 + n2 * 16];
    }

    float* lg = logits_out + (size_t)(bh * 1024 + q0 + rg * 16 + quad * 4) * 1024 + kw * 32 + col;

    const int sw0 = ((quad ^ (col & 7)) << 3);
    const int sw1 = (((quad + 4) ^ (col & 7)) << 3);

    __syncthreads();   // q/k0/v0 staged (implicit vmcnt(0) drain)
    bf16x8 af0 = *(const bf16x8*)&qs_ps[(rg * 16 + col) * 64 + sw0];
    bf16x8 af1 = *(const bf16x8*)&qs_ps[(rg * 16 + col) * 64 + sw1];
    __syncthreads();   // all waves read q before its LDS is reused as P

    __bf16* pw = &qs_ps[w * 640];     // 16 x 40 (pad) per-wave P buffer
    f32x4 o_acc[4];
#pragma unroll
    for (int i = 0; i < 4; i++) o_acc[i] = (f32x4){0.f, 0.f, 0.f, 0.f};
    float lsum[4] = {0.f, 0.f, 0.f, 0.f};

    const int swk = (((kw * 4 + quad) ^ (col & 7)) << 3);

    for (int kbi = 0; kbi < 16; kbi++) {
        if (kbi) __syncthreads();
        const int cur = kbi & 1;
        if (kbi < 15) {   // prefetch next k/v tile into other buffer
            const int nx = cur ^ 1;
            const __bf16* kgn = kg + (kbi + 1) * 4096;
            const __bf16* vgn = vg + (kbi + 1) * 64;
            async16(&kgn[r0 * 64 + sw], &ks[nx][w * 512]);
            async16(&kgn[(r0 + 32) * 64 + sw], &ks[nx][2048 + w * 512]);
            async16(&vgn[r0 * 1024 + sw], &vs[nx][w * 512]);
            async16(&vgn[(r0 + 32) * 1024 + sw], &vs[nx][2048 + w * 512]);
        }
        const __bf16* kc = ks[cur];
        const __bf16* vc = vs[cur];

        // S = q @ k^T : 16 rows x 32 keys (this wave's half)
        f32x4 s[2];
        s[0] = (f32x4){0.f, 0.f, 0.f, 0.f};
        s[1] = (f32x4){0.f, 0.f, 0.f, 0.f};
        {
            const int kr0 = (kw * 32 + col) * 64;
            const int kr1 = (kw * 32 + 16 + col) * 64;
            bf16x8 b00 = *(const bf16x8*)&kc[kr0 + sw0];
            bf16x8 b01 = *(const bf16x8*)&kc[kr0 + sw1];
            s[0] = __builtin_amdgcn_mfma_f32_16x16x32_bf16(af0, b00, s[0], 0, 0, 0);
            s[0] = __builtin_amdgcn_mfma_f32_16x16x32_bf16(af1, b01, s[0], 0, 0, 0);
            bf16x8 b10 = *(const bf16x8*)&kc[kr1 + sw0];
            bf16x8 b11 = *(const bf16x8*)&kc[kr1 + sw1];
            s[1] = __builtin_amdgcn_mfma_f32_16x16x32_bf16(af0, b10, s[1], 0, 0, 0);
            s[1] = __builtin_amdgcn_mfma_f32_16x16x32_bf16(af1, b11, s[1], 0, 0, 0);
        }

        // raw logits out; p = exp(raw + bias + nb) with pre-loaded regs
#pragma unroll
        for (int n2 = 0; n2 < 2; n2++) {
#pragma unroll
            for (int r = 0; r < 4; r++) {
                float raw = s[n2][r];
                __builtin_nontemporal_store(raw, &lg[r * 1024 + kbi * 64 + n2 * 16]);
                float p = __expf(raw + bv[n2] + nbv[n2][r]);
                lsum[r] += p;
                pw[(quad * 4 + r) * 40 + n2 * 16 + col] = (__bf16)p;
            }
        }
        // prefetch next iter's nb/bias (issued after this iter's async16s;
        // next barrier's vmcnt(0) drain completes them before use)
        if (kbi < 15) {
#pragma unroll
            for (int n2 = 0; n2 < 2; n2++) {
                bv[n2] = biasg[(kbi + 1) * 64 + n2 * 16];
#pragma unroll
                for (int r = 0; r < 4; r++)
                    nbv[n2][r] = nbg[r * 1024 + (kbi + 1) * 64 + n2 * 16];
            }
        }

        // O += P @ V over this wave's 32-key window
        bf16x8 pf = *(const bf16x8*)&pw[col * 40 + quad * 8];
#pragma unroll
        for (int ns = 0; ns < 4; ns++) {
            bf16x8 vf = *(const bf16x8*)&vc[(ns * 16 + col) * 64 + swk];
            o_acc[ns] = __builtin_amdgcn_mfma_f32_16x16x32_bf16(pf, vf, o_acc[ns], 0, 0, 0);
        }
    }

    // reduce lsum over the 16 cols of this wave
#pragma unroll
    for (int mask = 1; mask < 16; mask <<= 1)
#pragma unroll
        for (int r = 0; r < 4; r++) lsum[r] += __shfl_xor(lsum[r], mask);

    __syncthreads();   // all k/v reads done; reuse LDS for combine
    float* cO = (float*)&vs[0][0];   // 2 rowgroups x 16 rows x 64 c
    float* cL = (float*)&ks[0][0];   // 2 x 16 rows
    if (kw) {
#pragma unroll
        for (int ns = 0; ns < 4; ns++)
#pragma unroll
            for (int r = 0; r < 4; r++)
                cO[rg * 1024 + (quad * 4 + r) * 64 + ns * 16 + col] = o_acc[ns][r];
        if (col == 0)
#pragma unroll
            for (int r = 0; r < 4; r++) cL[rg * 16 + quad * 4 + r] = lsum[r];
    }
    __syncthreads();
    if (!kw) {
        float inv[4];
#pragma unroll
        for (int r = 0; r < 4; r++)
            inv[r] = 1.0f / (lsum[r] + cL[rg * 16 + quad * 4 + r]);
#pragma unroll
        for (int ns = 0; ns < 4; ns++) {
            const int c = ns * 16 + col;
#pragma unroll
            for (int r = 0; r < 4; r++) {
                const int pos = q0 + rg * 16 + quad * 4 + r;
                float ov = (o_acc[ns][r] + cO[rg * 1024 + (quad * 4 + r) * 64 + c]) * inv[r];
                float gv = (float)gate[(b * 1024 + pos) * 512 + h * 64 + c];
                wout[(b * 1024 + pos) * 512 + h * 64 + c] = f2bf(ov * gv);
            }
        }
    }
}

// ---------------------------------------------------------------------------
extern "C" void kernel_launch(void* const* d_in, const int* in_sizes, int n_in,
                              void* d_out, int out_size, void* d_ws, size_t ws_size,
                              hipStream_t stream) {
    (void)in_sizes; (void)n_in; (void)out_size; (void)ws_size;
    const float* q_data   = (const float*)d_in[0];
    const float* m_data   = (const float*)d_in[1];
    const float* bias     = (const float*)d_in[2];
    const float* nbb      = (const float*)d_in[3];
    const float* query_w  = (const float*)d_in[4];
    const float* key_w    = (const float*)d_in[5];
    const float* value_w  = (const float*)d_in[6];
    const float* gating_w = (const float*)d_in[7];
    const float* gating_b = (const float*)d_in[8];
    const float* output_w = (const float*)d_in[9];
    const float* output_b = (const float*)d_in[10];

    char* ws = (char*)d_ws;
    __bf16* qd_b  = (__bf16*)(ws + 0);         // 4 MiB (reused as wavg later)
    __bf16* md_b  = (__bf16*)(ws + 4194304);   // 4 MiB
    __bf16* qw_t  = (__bf16*)(ws + 8388608);   // 512 KiB each
    __bf16* kw_t  = (__bf16*)(ws + 8912896);
    __bf16* vw_t  = (__bf16*)(ws + 9437184);
    __bf16* gw_t  = (__bf16*)(ws + 9961472);
    __bf16* ow_t  = (__bf16*)(ws + 10485760);
    __bf16* q_buf = (__bf16*)(ws + 11010048);  // 4 MiB (b,h,pos,c)
    __bf16* k_buf = (__bf16*)(ws + 15204352);  // 4 MiB (b,h,pos,c)
    __bf16* v_t   = (__bf16*)(ws + 19398656);  // 4 MiB (b,h,c,pos)
    __bf16* gate  = (__bf16*)(ws + 23592960);  // 4 MiB (m,512)
    __bf16* wavg  = (__bf16*)(ws + 0);         // overlays qd_b (dead by then)

    float* outp = (float*)d_out;
    float* logits = outp + (4 * 1024 * 512);

    cast_data<<<dim3(1024), dim3(256), 0, stream>>>(q_data, m_data, qd_b, md_b);
    transpose_cast<<<dim3(8, 8, 5), dim3(256), 0, stream>>>(
        query_w, key_w, value_w, gating_w, output_w, qw_t, kw_t, vw_t, gw_t, ow_t);
    proj_gemm<<<dim3(32, 4, 4), dim3(256), 0, stream>>>(
        qd_b, md_b, qw_t, kw_t, vw_t, gw_t, q_buf, k_buf, v_t, gate, gating_b);
    attn_kernel<<<dim3(32, 32), dim3(256), 0, stream>>>(
        q_buf, k_buf, v_t, bias, nbb, gate, logits, wavg);
    out_gemm<<<dim3(32, 4), dim3(256), 0, stream>>>(wavg, ow_t, outp, output_b);
}